// Round 6
// baseline (250.888 us; speedup 1.0000x reference)
//
#include <hip/hip_runtime.h>

// Problem constants (fixed by the reference).
#define D      256        // vq_embed_dim == C
#define N_E    16384      // codebook size
#define NPTS   8192       // B*H*W
#define ZOUT   2097152    // elements of z_hat_out
#define MARGIN 2.0e-2f    // |err(d~)| sum bound, ~14 sigma each side
#define STRIPS 4          // 256-code strips per block
#define BIGF   3.0e38f

typedef short bf16x8 __attribute__((ext_vector_type(8)));
typedef unsigned short us8 __attribute__((ext_vector_type(8)));
typedef float f32x16 __attribute__((ext_vector_type(16)));
typedef unsigned long long u64;

__device__ __forceinline__ unsigned short f2bf(float x) {  // RNE
    unsigned int u = __float_as_uint(x);
    return (unsigned short)((u + 0x7FFFu + ((u >> 16) & 1u)) >> 16);
}
__device__ __forceinline__ unsigned int mono(float f) {     // order-preserving
    unsigned int u = __float_as_uint(f);
    return (u & 0x80000000u) ? ~u : (u | 0x80000000u);
}
__device__ __forceinline__ float demono(unsigned int u) {
    return __uint_as_float((u & 0x80000000u) ? (u ^ 0x80000000u) : ~u);
}
__device__ __forceinline__ void gl_lds16(const void* g, void* l) {
    __builtin_amdgcn_global_load_lds(
        (const __attribute__((address_space(1))) unsigned int*)g,
        (__attribute__((address_space(3))) unsigned int*)l, 16, 0, 0);
}

// ---------------------------------------------------------------------------
// Fused prep. Blocks [0,256): z (32 points each). Blocks [256,768): emb
// (32 codes each). Zpk = bf16(-2z), Epk = bf16(emb), in MFMA fragment-chunk
// layout (chunk (g,ks): 64 lanes x 16B, lane l = (row&31)+((k>>3)&1)*32).
// e2[j] = |emb_j|^2 fp32.
// ---------------------------------------------------------------------------
__global__ __launch_bounds__(256) void prep(
    const float* __restrict__ z, const float* __restrict__ emb,
    unsigned short* __restrict__ Zpk, unsigned short* __restrict__ Epk,
    float* __restrict__ e2) {
    const int t = threadIdx.x;
    if (blockIdx.x < 256) {
        const int n0 = blockIdx.x * 32;
        const int p = t & 31, ks8 = t >> 5;     // 8 k-slabs of 32
        const int n = n0 + p;
        const int b = n >> 10, hw = n & 1023;
        const float* zb = z + (size_t)b * 262144 + hw;
        const int k0 = ks8 * 32;
        float v[32];
        #pragma unroll
        for (int kk = 0; kk < 32; ++kk)
            v[kk] = zb[(size_t)(k0 + kk) * 1024];   // coalesced in p
        const int g = n >> 5;
        #pragma unroll
        for (int i = 0; i < 4; ++i) {               // 4 us8 per 32-k slab
            us8 hv;
            #pragma unroll
            for (int c = 0; c < 8; ++c) hv[c] = f2bf(-2.0f * v[i * 8 + c]);
            const int kabs = k0 + i * 8;
            const int ks = kabs >> 4;
            const int l = (n & 31) + ((kabs >> 3) & 1) * 32;
            *(us8*)(Zpk + ((size_t)(g * 16 + ks) * 64 + l) * 8) = hv;
        }
    } else {
        const int j0 = (blockIdx.x - 256) * 32;
        const int jj = j0 + (t >> 3), q = t & 7;    // 8 k-slabs of 32
        const float* row = emb + (size_t)jj * D + q * 32;
        float v[32];
        float s = 0.f;
        #pragma unroll
        for (int i = 0; i < 8; ++i) {
            const float4 x = *(const float4*)(row + i * 4);
            v[i * 4] = x.x; v[i * 4 + 1] = x.y; v[i * 4 + 2] = x.z; v[i * 4 + 3] = x.w;
            s += x.x * x.x + x.y * x.y + x.z * x.z + x.w * x.w;
        }
        const int g = jj >> 5;
        #pragma unroll
        for (int i = 0; i < 4; ++i) {
            us8 hv;
            #pragma unroll
            for (int c = 0; c < 8; ++c) hv[c] = f2bf(v[i * 8 + c]);
            const int kabs = q * 32 + i * 8;
            const int ks = kabs >> 4;
            const int l = (jj & 31) + ((kabs >> 3) & 1) * 32;
            *(us8*)(Epk + ((size_t)(g * 16 + ks) * 64 + l) * 8) = hv;
        }
        s += __shfl_xor(s, 1);
        s += __shfl_xor(s, 2);
        s += __shfl_xor(s, 4);
        if (q == 0) e2[jj] = s;
    }
}

// ---------------------------------------------------------------------------
// GEMM + per-(point, 64-code group) top-2. Block: 128 points (LDS) x
// STRIPS*256 codes; 4 waves, wave wid owns a distinct 64-code column.
// d~ = e2[code] + acc (Zpk holds -2z). Per group g (one per wave-strip):
// tkey[n][g] = mono(min1)<<32 | argmin_code; tm2[n][g] = min2.
// ---------------------------------------------------------------------------
__global__ __launch_bounds__(256, 2) void mfma_gemm(
    const unsigned short* __restrict__ Epk, const unsigned short* __restrict__ Zpk,
    const float* __restrict__ e2, u64* __restrict__ tkey,
    float* __restrict__ tm2) {
    __shared__ unsigned short Zbuf[64 * 512];   // 64 KB

    const int tid = threadIdx.x, lane = tid & 63, wid = tid >> 6;
    const int c32 = lane & 31, l5 = lane >> 5;
    const int n0 = blockIdx.x * 128;
    const int cs0 = blockIdx.y * (STRIPS * 256);

    #pragma unroll
    for (int ks = 0; ks < 16; ++ks)
        gl_lds16(Zpk + ((size_t)((n0 >> 5) + wid) * 16 + ks) * 512 + lane * 8,
                 Zbuf + (wid * 16 + ks) * 512);
    __syncthreads();   // single drain per block

    for (int s = 0; s < STRIPS; ++s) {
        const int cb = cs0 + s * 256 + wid * 64;   // this wave's 64 codes
        const unsigned short* eb = Epk + ((size_t)(cb >> 5) * 16) * 512 + lane * 8;
        const unsigned short* zb = Zbuf + lane * 8;

        f32x16 acc[2][4];
        const f32x16 z16 = {0.f};
        #pragma unroll
        for (int i = 0; i < 2; ++i)
            #pragma unroll
            for (int j = 0; j < 4; ++j) acc[i][j] = z16;

        bf16x8 ec[2], pc[4];
        ec[0] = *(const bf16x8*)(eb);
        ec[1] = *(const bf16x8*)(eb + 16 * 512);
        #pragma unroll
        for (int j = 0; j < 4; ++j) pc[j] = *(const bf16x8*)(zb + (j * 16) * 512);

        #pragma unroll 4
        for (int ks = 0; ks < 16; ++ks) {
            bf16x8 en[2], pn[4];
            if (ks < 15) {
                en[0] = *(const bf16x8*)(eb + (ks + 1) * 512);
                en[1] = *(const bf16x8*)(eb + (16 + ks + 1) * 512);
                #pragma unroll
                for (int j = 0; j < 4; ++j)
                    pn[j] = *(const bf16x8*)(zb + (j * 16 + ks + 1) * 512);
            }
            #pragma unroll
            for (int i = 0; i < 2; ++i)
                #pragma unroll
                for (int j = 0; j < 4; ++j)
                    acc[i][j] = __builtin_amdgcn_mfma_f32_32x32x16_bf16(
                        ec[i], pc[j], acc[i][j], 0, 0, 0);
            if (ks < 15) {
                ec[0] = en[0]; ec[1] = en[1];
                #pragma unroll
                for (int j = 0; j < 4; ++j) pc[j] = pn[j];
            }
        }

        // Epilogue: top-2 over this wave's 64 codes per point-lane.
        const int g = cb >> 6;
        float e2r[2][16];
        #pragma unroll
        for (int i = 0; i < 2; ++i)
            #pragma unroll
            for (int r = 0; r < 16; ++r)
                e2r[i][r] = e2[cb + i * 32 + (r & 3) + 8 * (r >> 2) + 4 * l5];
        #pragma unroll
        for (int j = 0; j < 4; ++j) {
            float m1 = e2r[0][0] + acc[0][j][0];
            int i1 = cb + 4 * l5;
            float m2 = BIGF;
            #pragma unroll
            for (int i = 0; i < 2; ++i)
                #pragma unroll
                for (int r = 0; r < 16; ++r) {
                    if (i == 0 && r == 0) continue;
                    const float v = e2r[i][r] + acc[i][j][r];
                    const int code = cb + i * 32 + (r & 3) + 8 * (r >> 2) + 4 * l5;
                    if (v < m1) { m2 = m1; m1 = v; i1 = code; }
                    else m2 = fminf(m2, v);
                }
            const float o1 = __shfl_xor(m1, 32);
            const float o2 = __shfl_xor(m2, 32);
            const int oi = __shfl_xor(i1, 32);
            if (o1 < m1) { m2 = fminf(m1, o2); m1 = o1; i1 = oi; }
            else         { m2 = fminf(o1, m2); }
            if (l5 == 0) {
                const int n = n0 + j * 32 + c32;
                tkey[(size_t)n * 256 + g] =
                    ((u64)mono(m1) << 32) | (unsigned int)i1;
                tm2[(size_t)n * 256 + g] = m2;
            }
        }
    }
}

// ---------------------------------------------------------------------------
// Rescore with certification. Per point (one wave): d1~,idx1 from min key;
// d2~ = min(winner group's min2, other groups' min1). If d2~-d1~ > MARGIN
// -> certified, emit idx1. Else exact fp32 rescan of groups with
// min1 <= d1~ + MARGIN (true winner provably included); tie -> lowest j.
// Emits idxf + total_idx. Zeroes loss.
// ---------------------------------------------------------------------------
__global__ __launch_bounds__(256) void rescore(
    const u64* __restrict__ tkey, const float* __restrict__ tm2,
    const float* __restrict__ z, const float* __restrict__ emb,
    const float* __restrict__ e2, int* __restrict__ idxf,
    float* __restrict__ out_idx, float* __restrict__ loss) {
    __shared__ float rbuf[4][256];
    const int tid = threadIdx.x, lane = tid & 63, w = tid >> 6;
    const int n = blockIdx.x * 4 + w;
    if (blockIdx.x == 0 && tid == 0) loss[0] = 0.f;

    u64 kv[4];
    float m2v[4];
    #pragma unroll
    for (int gi = 0; gi < 4; ++gi) {
        kv[gi] = tkey[(size_t)n * 256 + gi * 64 + lane];
        m2v[gi] = tm2[(size_t)n * 256 + gi * 64 + lane];
    }
    u64 k1 = kv[0];
    #pragma unroll
    for (int gi = 1; gi < 4; ++gi) k1 = kv[gi] < k1 ? kv[gi] : k1;
    #pragma unroll
    for (int st = 1; st < 64; st <<= 1) {
        const u64 o = __shfl_xor(k1, st);
        if (o < k1) k1 = o;
    }
    const float d1 = demono((unsigned int)(k1 >> 32));
    float d2 = BIGF;
    #pragma unroll
    for (int gi = 0; gi < 4; ++gi)
        d2 = fminf(d2, kv[gi] == k1 ? m2v[gi]
                                    : demono((unsigned int)(kv[gi] >> 32)));
    #pragma unroll
    for (int st = 1; st < 64; st <<= 1) d2 = fminf(d2, __shfl_xor(d2, st));

    int bi;
    if (d2 - d1 > MARGIN) {
        bi = (int)(unsigned int)(k1 & 0xFFFFFFFFull);   // certified
    } else {
        // Lazy-load residual r (wave-local LDS; no barrier needed in-wave).
        const int b = n >> 10, hw = n & 1023;
        #pragma unroll
        for (int kk = 0; kk < 4; ++kk)
            rbuf[w][lane + 64 * kk] =
                z[(size_t)b * 262144 + (size_t)(lane + 64 * kk) * 1024 + hw];
        const float thresh = d1 + MARGIN;
        u64 best = ~0ull;
        for (int gi = 0; gi < 4; ++gi) {
            u64 mask = __ballot(demono((unsigned int)(kv[gi] >> 32)) <= thresh);
            while (mask) {
                const int bit = (int)__builtin_ctzll(mask);
                mask &= mask - 1;
                const int c = (gi * 64 + bit) * 64 + lane;   // one code per lane
                const float* er = emb + (size_t)c * D;
                float s = 0.f;
                #pragma unroll
                for (int k = 0; k < 64; ++k) {
                    const float4 ev = *(const float4*)(er + k * 4);
                    s += rbuf[w][k * 4 + 0] * ev.x + rbuf[w][k * 4 + 1] * ev.y +
                         rbuf[w][k * 4 + 2] * ev.z + rbuf[w][k * 4 + 3] * ev.w;
                }
                const float d = e2[c] - 2.0f * s;
                const u64 key = ((u64)mono(d) << 32) | (unsigned int)c;
                if (key < best) best = key;
            }
        }
        #pragma unroll
        for (int st = 1; st < 64; st <<= 1) {
            const u64 o = __shfl_xor(best, st);
            if (o < best) best = o;
        }
        bi = (int)(unsigned int)(best & 0xFFFFFFFFull);
    }
    if (lane == 0) {
        idxf[n] = bi;
        const int b = n >> 10, hw = n & 1023;
        const float fv = (float)bi;
        #pragma unroll
        for (int sc = 0; sc < 4; ++sc) out_idx[b * 4096 + sc * 1024 + hw] = fv;
    }
}

// ---------------------------------------------------------------------------
// Gather q = emb[idx]; z_hat_out = z + (4q - z); loss accumulation.
// 1024 blocks: (4 c-tiles of 64) x (8 b x 32 hw-tiles). 256 thr = 32 hw x 8 cg.
// ---------------------------------------------------------------------------
__global__ __launch_bounds__(256) void quant_loss(
    const float* __restrict__ z, const float* __restrict__ emb,
    const int* __restrict__ idxf, float* __restrict__ out,
    float* __restrict__ loss) {
    __shared__ int idx_l[32];
    __shared__ float wsum[4];
    const int blk = blockIdx.x;
    const int c0 = (blk >> 8) * 64;
    const int rem = blk & 255;
    const int b = rem >> 5, hw0 = (rem & 31) * 32;
    const int t = threadIdx.x, hw_l = t & 31, cg = t >> 5;
    if (t < 32) idx_l[t] = idxf[b * 1024 + hw0 + t];
    __syncthreads();
    const int j = idx_l[hw_l];
    const float* er = emb + (size_t)j * D + c0 + cg * 8;
    const float4 q0 = *(const float4*)er;
    const float4 q1 = *(const float4*)(er + 4);
    const float qv[8] = {q0.x, q0.y, q0.z, q0.w, q1.x, q1.y, q1.z, q1.w};
    float e = 0.f;
    #pragma unroll
    for (int cc = 0; cc < 8; ++cc) {
        const int c = c0 + cg * 8 + cc;
        const size_t zi = (size_t)b * 262144 + (size_t)c * 1024 + hw0 + hw_l;
        const float zv = z[zi];
        const float q = qv[cc];
        const float zh = ((q + q) + q) + q;   // mimic 4-step accumulation
        out[zi] = zv + (zh - zv);
        e += 30.0f * q * q - 20.0f * q * zv + 4.0f * zv * zv;
    }
    #pragma unroll
    for (int off = 32; off > 0; off >>= 1) e += __shfl_down(e, off);
    if ((t & 63) == 0) wsum[t >> 6] = e;
    __syncthreads();
    if (t == 0) {
        const float s = wsum[0] + wsum[1] + wsum[2] + wsum[3];
        atomicAdd(loss, s * (0.3125f / 2097152.0f));
    }
}

// ---------------------------------------------------------------------------
extern "C" void kernel_launch(void* const* d_in, const int* in_sizes, int n_in,
                              void* d_out, int out_size, void* d_ws, size_t ws_size,
                              hipStream_t stream) {
    const float* z = (const float*)d_in[0];     // [8,256,32,32]
    const float* emb = (const float*)d_in[1];   // [16384,256]
    float* out = (float*)d_out;                 // z_hat_out | loss | total_idx

    // Workspace (~38 MB)
    unsigned short* Zpk = (unsigned short*)d_ws;            // 8192*256 bf16
    unsigned short* Epk = Zpk + (size_t)NPTS * D;           // 16384*256 bf16
    float* e2 = (float*)(Epk + (size_t)N_E * D);            // 16384 f32
    u64* tkey = (u64*)(e2 + N_E);                           // 8192*256 u64
    float* tm2 = (float*)(tkey + (size_t)NPTS * 256);       // 8192*256 f32
    int* idxf = (int*)(tm2 + (size_t)NPTS * 256);           // 8192 i32

    float* loss = out + ZOUT;
    float* out_idx = out + ZOUT + 1;

    prep<<<768, 256, 0, stream>>>(z, emb, Zpk, Epk, e2);
    mfma_gemm<<<dim3(NPTS / 128, N_E / (256 * STRIPS)), 256, 0, stream>>>(
        Epk, Zpk, e2, tkey, tm2);
    rescore<<<NPTS / 4, 256, 0, stream>>>(tkey, tm2, z, emb, e2, idxf, out_idx,
                                          loss);
    quant_loss<<<1024, 256, 0, stream>>>(z, emb, idxf, out, loss);
}